// Round 8
// baseline (124.999 us; speedup 1.0000x reference)
//
#include <hip/hip_runtime.h>
#include <hip/hip_bf16.h>

typedef __attribute__((ext_vector_type(4))) float f32x4;
typedef __attribute__((ext_vector_type(8))) short s16x8;
typedef __attribute__((ext_vector_type(4))) unsigned short u16x4;
typedef __attribute__((ext_vector_type(8))) __bf16 bf16x8;

#define HDIM 512
#define SEQ  2048
#define NB   64
#define BM   64
#define NBLK ((NB * SEQ) / BM)   // 2048 blocks
#define CPB  (SEQ / BM)          // 32 chunks per batch

// round-to-nearest-even fp32 -> bf16 bits
static __device__ __forceinline__ unsigned short f2bf(float f) {
  unsigned u = __float_as_uint(f);
  u += 0x7fffu + ((u >> 16) & 1u);
  return (unsigned short)(u >> 16);
}
static __device__ __forceinline__ float bf2f(unsigned short v) {
  return __uint_as_float(((unsigned)v) << 16);
}

static __device__ __forceinline__ f32x4 mfma16(s16x8 a, s16x8 b, f32x4 c) {
  return __builtin_amdgcn_mfma_f32_16x16x32_bf16(
      __builtin_bit_cast(bf16x8, a), __builtin_bit_cast(bf16x8, b), c, 0, 0, 0);
}

// 4 B-fragment loads for one k-step: SGPR base sp, shared voffset, imm per nf.
#define BLOADG(dst, sp)                                                        \
  do {                                                                         \
    asm volatile("global_load_dwordx4 %0, %1, %2 offset:0"                     \
                 : "=&v"((dst)[0]) : "v"(voff), "s"(sp));                      \
    asm volatile("global_load_dwordx4 %0, %1, %2 offset:1024"                  \
                 : "=&v"((dst)[1]) : "v"(voff), "s"(sp));                      \
    asm volatile("global_load_dwordx4 %0, %1, %2 offset:2048"                  \
                 : "=&v"((dst)[2]) : "v"(voff), "s"(sp));                      \
    asm volatile("global_load_dwordx4 %0, %1, %2 offset:3072"                  \
                 : "=&v"((dst)[3]) : "v"(voff), "s"(sp));                      \
  } while (0)

// one A-slice staging load (16B fp32 per thread) for slice s
#define SLOAD(dst, s)                                                          \
  asm volatile("global_load_dwordx4 %0, %1, %2"                                \
               : "=&v"(dst) : "v"(aoff), "s"(encblk + (s) * 32))

// pack+write one staged slice s into the swizzled A tile
#define PACKW(src, s)                                                          \
  do {                                                                         \
    u16x4 pk;                                                                  \
    pk.x = f2bf((src).x); pk.y = f2bf((src).y);                                \
    pk.z = f2bf((src).z); pk.w = f2bf((src).w);                                \
    *(u16x4*)((char*)Asm + wrow * 1024 +                                       \
              (((((s) * 4) + (wc >> 1)) ^ wr7) * 16) + (wc & 1) * 8) = pk;     \
  } while (0)

// ---------------- kernel 0a: W1 fp32 -> bf16, k-step-major -------------------
__global__ void convert_w1(const float* __restrict__ w1,
                           unsigned short* __restrict__ o) {
  int id = blockIdx.x * 256 + threadIdx.x;   // 32768 chunks of 16B
  int kk = id >> 11, n = (id >> 2) & 511, r4 = id & 3;
  const float* src = w1 + (long)n * HDIM + kk * 32 + r4 * 8;
  f32x4 v0 = *(const f32x4*)src;
  f32x4 v1 = *(const f32x4*)(src + 4);
  u16x4 a, b;
  a.x = f2bf(v0.x); a.y = f2bf(v0.y); a.z = f2bf(v0.z); a.w = f2bf(v0.w);
  b.x = f2bf(v1.x); b.y = f2bf(v1.y); b.z = f2bf(v1.z); b.w = f2bf(v1.w);
  unsigned short* dst = o + (long)id * 8;
  *(u16x4*)dst = a;
  *(u16x4*)(dst + 4) = b;
}

// ---------------- kernel 0b: z[b][o] = dec[b]·W2[o] + b2[o] + b1[o] ----------
__global__ void zproj(const float* __restrict__ dec, const float* __restrict__ W2,
                      const float* __restrict__ b1, const float* __restrict__ b2,
                      float* __restrict__ zfull) {
  int b = blockIdx.x, oc = blockIdx.y, tid = threadIdx.x;
  int o = oc * 256 + tid;
  __shared__ float d_s[HDIM];
  d_s[tid] = dec[b * HDIM + tid];
  d_s[tid + 256] = dec[b * HDIM + tid + 256];
  __syncthreads();
  const float* w = W2 + (long)o * HDIM;
  float s = 0.f;
#pragma unroll 4
  for (int k = 0; k < HDIM; k += 4) {
    f32x4 v = *(const f32x4*)(w + k);
    s += v.x * d_s[k] + v.y * d_s[k + 1] + v.z * d_s[k + 2] + v.w * d_s[k + 3];
  }
  zfull[b * HDIM + o] = s + b1[o] + b2[o];
}

// ------ kernel 1: fused GEMM + tanh + V-dot + local softmax + partial ctx ----
// In-loop A staging: slice kk+4 asm-loaded, slice kk+3 packed+written, slice kk
// computed. One raw s_barrier/iter (no vmcnt drain); counted vmcnt(5).
__global__ __launch_bounds__(512, 4)
void gemm_fused(const float* __restrict__ enc, const unsigned short* __restrict__ w1k,
                const float* __restrict__ zfull, const float* __restrict__ V,
                const float* __restrict__ bv, float* __restrict__ scores,
                unsigned short* __restrict__ pctx, float* __restrict__ ml) {
  __shared__ __align__(16) char pool[71936];
  unsigned short* Asm = (unsigned short*)pool;            // 64 KiB bf16 tile
  float* zbuf = (float*)(pool + 65536);                   // 512 f
  float* vbuf = (float*)(pool + 67584);                   // 512 f
  float* red  = (float*)(pool + 69632);                   // 8*64 f
  float* plds = (float*)(pool + 71680);                   // 64 f
  float* pcr  = (float*)pool;                             // overlays A after reads

  const int tid = threadIdx.x;
  const int wid = tid >> 6;
  const int lane = tid & 63;
  const long m0 = (long)blockIdx.x * BM;
  const int b = (int)(m0 >> 11);

  zbuf[tid] = zfull[b * HDIM + tid];
  vbuf[tid] = V[tid];

  const int r4 = lane >> 4, c15 = lane & 15, c7 = c15 & 7;
  const char* Ab = (const char*)Asm;
  const unsigned voff = (unsigned)((wid * 64 + c15) * 64 + r4 * 16);

  // staging addressing (const per thread): row = tid>>3, 16B-f32 chunk c=tid&7
  const int wrow = tid >> 3, wc = tid & 7, wr7 = wrow & 7;
  const float* encblk = enc + m0 * HDIM;
  const unsigned aoff = (unsigned)(wrow * 2048 + wc * 16);

  // ---- prologue: slices 0..2 staged with plain loads (before any asm vmem) --
  {
    const float* ep = encblk + (long)wrow * HDIM + wc * 4;
#pragma unroll
    for (int s = 0; s < 3; ++s) {
      f32x4 v = *(const f32x4*)(ep + s * 32);
      PACKW(v, s);
    }
  }
  __syncthreads();   // drains everything; asm queue starts clean

  f32x4 acc[4][4] = {};
  s16x8 bX[4], bY[4];
  f32x4 sb0, sb1;

  SLOAD(sb1, 3);                 // slice 3 (as if iter -1)
  BLOADG(bX, w1k);               // k-step 0

  // ---- K-loop: per-iter {S-issue, B-issue, vmcnt(5), pack, barrier, MFMA} ---
#pragma unroll
  for (int kk = 0; kk < 16; ++kk) {
    // a) staging load slice kk+4
    if (kk <= 11) {
      if (kk & 1) SLOAD(sb1, kk + 4); else SLOAD(sb0, kk + 4);
    }
    // b) B loads k-step kk+1
    if (kk <= 14) {
      const unsigned short* sp = w1k + (kk + 1) * 16384;
      if (kk & 1) BLOADG(bX, sp); else BLOADG(bY, sp);
    }
    // c) counted wait: drains B(kk) + S(kk+3); leaves S(kk+4)+B(kk+1) in flight
    if (kk <= 11)      asm volatile("s_waitcnt vmcnt(5)" ::: "memory");
    else if (kk <= 14) asm volatile("s_waitcnt vmcnt(4)" ::: "memory");
    else               asm volatile("s_waitcnt vmcnt(0)" ::: "memory");
    __builtin_amdgcn_sched_barrier(0);   // packs/MFMA must not cross the wait
    // d) pack + ds_write slice kk+3 (loaded last iter into the other buffer)
    if (kk <= 12) {
      if (kk & 1) PACKW(sb0, kk + 3); else PACKW(sb1, kk + 3);
    }
    // e) flush writes, barrier (no vmcnt drain), wall
    asm volatile("s_waitcnt lgkmcnt(0)" ::: "memory");
    __builtin_amdgcn_s_barrier();
    __builtin_amdgcn_sched_barrier(0);
    // f) MFMA cluster on slice kk (written 3 barriers ago)
    const int abase = c15 * 1024 + (((kk * 4 + r4) ^ c7) * 16);
    __builtin_amdgcn_s_setprio(1);
#pragma unroll
    for (int mf = 0; mf < 4; ++mf) {
      s16x8 af = *(const s16x8*)(Ab + abase + mf * 16384);
      if (kk & 1) {
#pragma unroll
        for (int nf = 0; nf < 4; ++nf) acc[mf][nf] = mfma16(af, bY[nf], acc[mf][nf]);
      } else {
#pragma unroll
        for (int nf = 0; nf < 4; ++nf) acc[mf][nf] = mfma16(af, bX[nf], acc[mf][nf]);
      }
    }
    __builtin_amdgcn_s_setprio(0);
  }

  // ---- epilogue 1: scores[m] = sum_n tanh(acc + z[n]) * V[n] + bv ----
  // C/D layout (16x16x32): col = lane&15, row = (lane>>4)*4 + j   [m89/m91]
  float zr[4], vr[4];
#pragma unroll
  for (int nf = 0; nf < 4; ++nf) {
    const int n = wid * 64 + nf * 16 + c15;
    zr[nf] = zbuf[n];
    vr[nf] = vbuf[n];
  }
#pragma unroll
  for (int mf = 0; mf < 4; ++mf) {
#pragma unroll
    for (int j = 0; j < 4; ++j) {
      float s = 0.f;
#pragma unroll
      for (int nf = 0; nf < 4; ++nf) {
        float x = acc[mf][nf][j] + zr[nf];
        float e = __expf(2.f * x);
        float t = 1.f - 2.f * __builtin_amdgcn_rcpf(e + 1.f);  // tanh(x)
        s += t * vr[nf];
      }
      s += __shfl_xor(s, 1); s += __shfl_xor(s, 2);
      s += __shfl_xor(s, 4); s += __shfl_xor(s, 8);
      if (c15 == 0) red[wid * BM + mf * 16 + r4 * 4 + j] = s;
    }
  }
  __syncthreads();

  // ---- epilogue 2: wave 0 finishes scores + local softmax stats ----
  if (tid < BM) {
    float s = 0.f;
#pragma unroll
    for (int w = 0; w < 8; ++w) s += red[w * BM + tid];
    s += bv[0];
    scores[m0 + tid] = s;                       // raw score
    float mc = s;
#pragma unroll
    for (int off = 1; off < 64; off <<= 1) mc = fmaxf(mc, __shfl_xor(mc, off));
    float p = __expf(s - mc);
    plds[tid] = p;
    float lc = p;
#pragma unroll
    for (int off = 1; off < 64; off <<= 1) lc += __shfl_xor(lc, off);
    if (tid == 0) { ml[blockIdx.x * 2] = mc; ml[blockIdx.x * 2 + 1] = lc; }
  }
  __syncthreads();

  // ---- epilogue 3: pctx[h] = sum_s p[s]*A[s][h], vector LDS reads ----
  float c8[8] = {};
#pragma unroll
  for (int rr = 0; rr < 8; ++rr) {
    const int r = wid * 8 + rr;
    s16x8 v = *(const s16x8*)(Ab + r * 1024 + ((lane ^ rr) * 16));
    const float p = plds[r];
#pragma unroll
    for (int e = 0; e < 8; ++e)
      c8[e] += p * bf2f((unsigned short)v[e]);
  }
  __syncthreads();   // all A reads done; safe to overlay pcr on A region
  {
    f32x4 w0, w1;
    w0.x = c8[0]; w0.y = c8[1]; w0.z = c8[2]; w0.w = c8[3];
    w1.x = c8[4]; w1.y = c8[5]; w1.z = c8[6]; w1.w = c8[7];
    *(f32x4*)((char*)pcr + wid * 2048 + lane * 32) = w0;
    *(f32x4*)((char*)pcr + wid * 2048 + lane * 32 + 16) = w1;
  }
  __syncthreads();
  {
    float s = 0.f;
#pragma unroll
    for (int g = 0; g < 8; ++g) s += pcr[g * 512 + tid];
    pctx[(long)blockIdx.x * HDIM + tid] = f2bf(s);
  }
}

// ---------------- kernel 2: combine partials -> attn (in place) + ctx --------
__global__ void combine(float* __restrict__ attn, const unsigned short* __restrict__ pctx,
                        const float* __restrict__ ml, float* __restrict__ ctx) {
  const int b = blockIdx.x, tid = threadIdx.x;   // 512 threads
  const int lane = tid & 63;
  float m = -1e30f, l = 0.f;
  if (lane < CPB) {
    m = ml[(b * CPB + lane) * 2];
    l = ml[(b * CPB + lane) * 2 + 1];
  }
  float M = m;
#pragma unroll
  for (int off = 1; off < 64; off <<= 1) M = fmaxf(M, __shfl_xor(M, off));
  float le = (lane < CPB) ? l * __expf(m - M) : 0.f;
  float L = le;
#pragma unroll
  for (int off = 1; off < 64; off <<= 1) L += __shfl_xor(L, off);
  const float invL = 1.f / L;

  __shared__ float wc[CPB];
  if (tid < CPB) wc[tid] = __expf(ml[(b * CPB + tid) * 2] - M) * invL;

  // attn rescale in place: attn currently holds raw scores
  float sv[4];
#pragma unroll
  for (int i = 0; i < 4; ++i) sv[i] = attn[(long)b * SEQ + i * 512 + tid];
#pragma unroll
  for (int i = 0; i < 4; ++i)
    attn[(long)b * SEQ + i * 512 + tid] = __expf(sv[i] - M) * invL;

  __syncthreads();
  // ctx[h] = sum_c pctx[c][h] * wc[c]
  float a = 0.f;
#pragma unroll 8
  for (int c = 0; c < CPB; ++c)
    a += bf2f(pctx[(long)(b * CPB + c) * HDIM + tid]) * wc[c];
  ctx[(long)b * HDIM + tid] = a;
}

extern "C" void kernel_launch(void* const* d_in, const int* in_sizes, int n_in,
                              void* d_out, int out_size, void* d_ws, size_t ws_size,
                              hipStream_t stream) {
  const float* enc = (const float*)d_in[0];
  const float* dec = (const float*)d_in[1];
  const float* W1  = (const float*)d_in[2];
  const float* b1  = (const float*)d_in[3];
  const float* W2  = (const float*)d_in[4];
  const float* b2  = (const float*)d_in[5];
  const float* V   = (const float*)d_in[6];
  const float* bv  = (const float*)d_in[7];

  float* out  = (float*)d_out;
  float* ctx  = out;                       // 64*512
  float* attn = out + NB * HDIM;           // 64*2048 (raw scores first, rescaled in place)

  char* ws = (char*)d_ws;
  unsigned short* w1k  = (unsigned short*)ws;                   // 512 KiB (k-step-major)
  float*          zful = (float*)(ws + 524288);                 // 128 KiB
  unsigned short* pctx = (unsigned short*)(ws + 655360);        // 2 MiB  (2048*512 bf16)
  float*          mlb  = (float*)(ws + 2752512);                // 16 KiB (2048*2 f32)
  (void)in_sizes; (void)n_in; (void)out_size; (void)ws_size;

  convert_w1<<<128, 256, 0, stream>>>(W1, w1k);
  zproj<<<dim3(NB, 2), 256, 0, stream>>>(dec, W2, b1, b2, zful);
  gemm_fused<<<NBLK, 512, 0, stream>>>(enc, w1k, zful, V, bv, attn, pctx, mlb);
  combine<<<NB, 512, 0, stream>>>(attn, pctx, mlb, ctx);
}

// Round 9
// 118.060 us; speedup vs baseline: 1.0588x; 1.0588x over previous
//
#include <hip/hip_runtime.h>
#include <hip/hip_bf16.h>

typedef __attribute__((ext_vector_type(4))) float f32x4;
typedef __attribute__((ext_vector_type(8))) short s16x8;
typedef __attribute__((ext_vector_type(4))) unsigned short u16x4;
typedef __attribute__((ext_vector_type(8))) __bf16 bf16x8;

#define HDIM 512
#define SEQ  2048
#define NB   64
#define BM   64
#define NBLK ((NB * SEQ) / BM)   // 2048 blocks
#define CPB  (SEQ / BM)          // 32 chunks per batch

// round-to-nearest-even fp32 -> bf16 bits
static __device__ __forceinline__ unsigned short f2bf(float f) {
  unsigned u = __float_as_uint(f);
  u += 0x7fffu + ((u >> 16) & 1u);
  return (unsigned short)(u >> 16);
}
static __device__ __forceinline__ float bf2f(unsigned short v) {
  return __uint_as_float(((unsigned)v) << 16);
}

static __device__ __forceinline__ f32x4 mfma16(s16x8 a, s16x8 b, f32x4 c) {
  return __builtin_amdgcn_mfma_f32_16x16x32_bf16(
      __builtin_bit_cast(bf16x8, a), __builtin_bit_cast(bf16x8, b), c, 0, 0, 0);
}

// 4 B-fragment loads for one k-step: SGPR base sp, shared voffset, imm per nf.
#define BLOADG(dst, sp)                                                        \
  do {                                                                         \
    asm volatile("global_load_dwordx4 %0, %1, %2 offset:0"                     \
                 : "=&v"((dst)[0]) : "v"(voff), "s"(sp));                      \
    asm volatile("global_load_dwordx4 %0, %1, %2 offset:1024"                  \
                 : "=&v"((dst)[1]) : "v"(voff), "s"(sp));                      \
    asm volatile("global_load_dwordx4 %0, %1, %2 offset:2048"                  \
                 : "=&v"((dst)[2]) : "v"(voff), "s"(sp));                      \
    asm volatile("global_load_dwordx4 %0, %1, %2 offset:3072"                  \
                 : "=&v"((dst)[3]) : "v"(voff), "s"(sp));                      \
  } while (0)

// one A-slice staging load (16B fp32 per thread) for slice s
#define SLOAD(dst, s)                                                          \
  asm volatile("global_load_dwordx4 %0, %1, %2"                                \
               : "=&v"(dst) : "v"(aoff), "s"(encblk + (s) * 32))

#define WAITV(N)                                                               \
  do {                                                                         \
    asm volatile("s_waitcnt vmcnt(%0)" :: "i"(N) : "memory");                  \
    __builtin_amdgcn_sched_barrier(0);                                         \
  } while (0)

// pack+write one staged slice s into the swizzled A tile
#define PACKW(src, s)                                                          \
  do {                                                                         \
    u16x4 pk;                                                                  \
    pk.x = f2bf((src).x); pk.y = f2bf((src).y);                                \
    pk.z = f2bf((src).z); pk.w = f2bf((src).w);                                \
    *(u16x4*)((char*)Asm + wrow * 1024 +                                       \
              (((((s) * 4) + (wc >> 1)) ^ wr7) * 16) + (wc & 1) * 8) = pk;     \
  } while (0)

// ---------------- kernel 0: fused W1-convert + zproj -------------------------
// blocks 0..127: W1 fp32 -> bf16 k-step-major (chunk id = kk*2048 + n*4 + r4).
// blocks 128..255: z[b][o] = dec[b]·W2[o] + b2[o] + b1[o].
__global__ void prep(const float* __restrict__ w1, unsigned short* __restrict__ o,
                     const float* __restrict__ dec, const float* __restrict__ W2,
                     const float* __restrict__ b1, const float* __restrict__ b2,
                     float* __restrict__ zfull) {
  const int bx = blockIdx.x, tid = threadIdx.x;
  if (bx < 128) {
    int id = bx * 256 + tid;   // 32768 chunks of 16B
    int kk = id >> 11, n = (id >> 2) & 511, r4 = id & 3;
    const float* src = w1 + (long)n * HDIM + kk * 32 + r4 * 8;
    f32x4 v0 = *(const f32x4*)src;
    f32x4 v1 = *(const f32x4*)(src + 4);
    u16x4 a, b;
    a.x = f2bf(v0.x); a.y = f2bf(v0.y); a.z = f2bf(v0.z); a.w = f2bf(v0.w);
    b.x = f2bf(v1.x); b.y = f2bf(v1.y); b.z = f2bf(v1.z); b.w = f2bf(v1.w);
    unsigned short* dst = o + (long)id * 8;
    *(u16x4*)dst = a;
    *(u16x4*)(dst + 4) = b;
  } else {
    const int idx = bx - 128;
    const int b = idx >> 1, oc = idx & 1;
    const int oo = oc * 256 + tid;
    __shared__ float d_s[HDIM];
    d_s[tid] = dec[b * HDIM + tid];
    d_s[tid + 256] = dec[b * HDIM + tid + 256];
    __syncthreads();
    const float* w = W2 + (long)oo * HDIM;
    float s = 0.f;
#pragma unroll 4
    for (int k = 0; k < HDIM; k += 4) {
      f32x4 v = *(const f32x4*)(w + k);
      s += v.x * d_s[k] + v.y * d_s[k + 1] + v.z * d_s[k + 2] + v.w * d_s[k + 3];
    }
    zfull[b * HDIM + oo] = s + b1[oo] + b2[oo];
  }
}

// ------ kernel 1: fused GEMM + tanh + V-dot + local softmax + partial ctx ----
// Deep-queue prologue A staging; barrier-free wave-rotated K-loop with
// per-fragment vmcnt staircase (nf-major MFMA order).
__global__ __launch_bounds__(512, 4)
void gemm_fused(const float* __restrict__ enc, const unsigned short* __restrict__ w1k,
                const float* __restrict__ zfull, const float* __restrict__ V,
                const float* __restrict__ bv, float* __restrict__ scores,
                unsigned short* __restrict__ pctx, float* __restrict__ ml) {
  __shared__ __align__(16) char pool[67840];
  unsigned short* Asm = (unsigned short*)pool;            // 64 KiB bf16 tile
  float* red  = (float*)(pool + 65536);                   // 8*64 f
  float* plds = (float*)(pool + 67584);                   // 64 f
  float* pcr  = (float*)pool;                             // overlays A after reads

  const int tid = threadIdx.x;
  const int wid = tid >> 6;
  const int lane = tid & 63;
  const long m0 = (long)blockIdx.x * BM;
  const int b = (int)(m0 >> 11);

  const int r4 = lane >> 4, c15 = lane & 15, c7 = c15 & 7;
  const char* Ab = (const char*)Asm;
  const unsigned voff = (unsigned)((wid * 64 + c15) * 64 + r4 * 16);
  const int widu = __builtin_amdgcn_readfirstlane(wid);

  // staging addressing: row = tid>>3, 16B-f32 chunk wc = tid&7
  const int wrow = tid >> 3, wc = tid & 7, wr7 = wrow & 7;
  const float* encblk = enc + m0 * HDIM;
  const unsigned aoff = (unsigned)(wrow * 2048 + wc * 16);

  // ---- prologue: stage all 16 A slices, 8 loads outstanding ----
  {
    f32x4 pa, pb, pc, pd, pe, pf, pg, ph;
    SLOAD(pa, 0); SLOAD(pb, 1); SLOAD(pc, 2); SLOAD(pd, 3);
    SLOAD(pe, 4); SLOAD(pf, 5); SLOAD(pg, 6); SLOAD(ph, 7);
    WAITV(4);
    PACKW(pa, 0); PACKW(pb, 1); PACKW(pc, 2); PACKW(pd, 3);
    SLOAD(pa, 8); SLOAD(pb, 9); SLOAD(pc, 10); SLOAD(pd, 11);
    WAITV(4);
    PACKW(pe, 4); PACKW(pf, 5); PACKW(pg, 6); PACKW(ph, 7);
    SLOAD(pe, 12); SLOAD(pf, 13); SLOAD(pg, 14); SLOAD(ph, 15);
    WAITV(4);
    PACKW(pa, 8); PACKW(pb, 9); PACKW(pc, 10); PACKW(pd, 11);
    WAITV(0);
    PACKW(pe, 12); PACKW(pf, 13); PACKW(pg, 14); PACKW(ph, 15);
  }
  __syncthreads();   // A tile visible; vm queue clean

  f32x4 acc[4][4] = {};
  s16x8 bX[4], bY[4];

  // prefetch this wave's first (rotated) k-step
  BLOADG(bX, w1k + ((widu & 15) * 16384));

  // ---- K-loop: barrier-free, nf-major vmcnt staircase ----
#pragma unroll
  for (int kk = 0; kk < 16; ++kk) {
    const int ke = (kk + widu) & 15;
    s16x8* cur = (kk & 1) ? bY : bX;
    s16x8* nxt = (kk & 1) ? bX : bY;

    s16x8 af[4];
    const int abase = c15 * 1024 + (((ke * 4 + r4) ^ c7) * 16);
#pragma unroll
    for (int mf = 0; mf < 4; ++mf)
      af[mf] = *(const s16x8*)(Ab + abase + mf * 16384);

    if (kk < 15)
      BLOADG(nxt, w1k + ((((kk + 1) + widu) & 15) * 16384));

    __builtin_amdgcn_s_setprio(1);
    if (kk < 15) {
      WAITV(7);
#pragma unroll
      for (int mf = 0; mf < 4; ++mf) acc[mf][0] = mfma16(af[mf], cur[0], acc[mf][0]);
      WAITV(6);
#pragma unroll
      for (int mf = 0; mf < 4; ++mf) acc[mf][1] = mfma16(af[mf], cur[1], acc[mf][1]);
      WAITV(5);
#pragma unroll
      for (int mf = 0; mf < 4; ++mf) acc[mf][2] = mfma16(af[mf], cur[2], acc[mf][2]);
      WAITV(4);
#pragma unroll
      for (int mf = 0; mf < 4; ++mf) acc[mf][3] = mfma16(af[mf], cur[3], acc[mf][3]);
    } else {
      WAITV(3);
#pragma unroll
      for (int mf = 0; mf < 4; ++mf) acc[mf][0] = mfma16(af[mf], cur[0], acc[mf][0]);
      WAITV(2);
#pragma unroll
      for (int mf = 0; mf < 4; ++mf) acc[mf][1] = mfma16(af[mf], cur[1], acc[mf][1]);
      WAITV(1);
#pragma unroll
      for (int mf = 0; mf < 4; ++mf) acc[mf][2] = mfma16(af[mf], cur[2], acc[mf][2]);
      WAITV(0);
#pragma unroll
      for (int mf = 0; mf < 4; ++mf) acc[mf][3] = mfma16(af[mf], cur[3], acc[mf][3]);
    }
    __builtin_amdgcn_s_setprio(0);
  }

  // ---- epilogue 1: scores[m] = sum_n tanh(acc + z[n]) * V[n] + bv ----
  // C/D layout (16x16x32): col = lane&15, row = (lane>>4)*4 + j   [m89/m91]
  float zr[4], vr[4];
#pragma unroll
  for (int nf = 0; nf < 4; ++nf) {
    const int n = wid * 64 + nf * 16 + c15;
    zr[nf] = zfull[b * HDIM + n];
    vr[nf] = V[n];
  }
#pragma unroll
  for (int mf = 0; mf < 4; ++mf) {
#pragma unroll
    for (int j = 0; j < 4; ++j) {
      float s = 0.f;
#pragma unroll
      for (int nf = 0; nf < 4; ++nf) {
        float x = acc[mf][nf][j] + zr[nf];
        float e = __expf(2.f * x);
        float t = 1.f - 2.f * __builtin_amdgcn_rcpf(e + 1.f);  // tanh(x)
        s += t * vr[nf];
      }
      s += __shfl_xor(s, 1); s += __shfl_xor(s, 2);
      s += __shfl_xor(s, 4); s += __shfl_xor(s, 8);
      if (c15 == 0) red[wid * BM + mf * 16 + r4 * 4 + j] = s;
    }
  }
  __syncthreads();

  // ---- epilogue 2: wave 0 finishes scores + local softmax stats ----
  if (tid < BM) {
    float s = 0.f;
#pragma unroll
    for (int w = 0; w < 8; ++w) s += red[w * BM + tid];
    s += bv[0];
    scores[m0 + tid] = s;                       // raw score
    float mc = s;
#pragma unroll
    for (int off = 1; off < 64; off <<= 1) mc = fmaxf(mc, __shfl_xor(mc, off));
    float p = __expf(s - mc);
    plds[tid] = p;
    float lc = p;
#pragma unroll
    for (int off = 1; off < 64; off <<= 1) lc += __shfl_xor(lc, off);
    if (tid == 0) { ml[blockIdx.x * 2] = mc; ml[blockIdx.x * 2 + 1] = lc; }
  }
  __syncthreads();

  // ---- epilogue 3: pctx[h] = sum_s p[s]*A[s][h], vector LDS reads ----
  float c8[8] = {};
#pragma unroll
  for (int rr = 0; rr < 8; ++rr) {
    const int r = wid * 8 + rr;
    s16x8 v = *(const s16x8*)(Ab + r * 1024 + ((lane ^ rr) * 16));
    const float p = plds[r];
#pragma unroll
    for (int e = 0; e < 8; ++e)
      c8[e] += p * bf2f((unsigned short)v[e]);
  }
  __syncthreads();   // all A reads done; safe to overlay pcr on A region
  {
    f32x4 w0, w1;
    w0.x = c8[0]; w0.y = c8[1]; w0.z = c8[2]; w0.w = c8[3];
    w1.x = c8[4]; w1.y = c8[5]; w1.z = c8[6]; w1.w = c8[7];
    *(f32x4*)((char*)pcr + wid * 2048 + lane * 32) = w0;
    *(f32x4*)((char*)pcr + wid * 2048 + lane * 32 + 16) = w1;
  }
  __syncthreads();
  {
    float s = 0.f;
#pragma unroll
    for (int g = 0; g < 8; ++g) s += pcr[g * 512 + tid];
    pctx[(long)blockIdx.x * HDIM + tid] = f2bf(s);
  }
}

// ---------------- kernel 2: combine partials -> attn (in place) + ctx --------
__global__ void combine(float* __restrict__ attn, const unsigned short* __restrict__ pctx,
                        const float* __restrict__ ml, float* __restrict__ ctx) {
  const int b = blockIdx.x, tid = threadIdx.x;   // 512 threads
  const int lane = tid & 63;
  float m = -1e30f, l = 0.f;
  if (lane < CPB) {
    m = ml[(b * CPB + lane) * 2];
    l = ml[(b * CPB + lane) * 2 + 1];
  }
  float M = m;
#pragma unroll
  for (int off = 1; off < 64; off <<= 1) M = fmaxf(M, __shfl_xor(M, off));
  float le = (lane < CPB) ? l * __expf(m - M) : 0.f;
  float L = le;
#pragma unroll
  for (int off = 1; off < 64; off <<= 1) L += __shfl_xor(L, off);
  const float invL = 1.f / L;

  __shared__ float wc[CPB];
  if (tid < CPB) wc[tid] = __expf(ml[(b * CPB + tid) * 2] - M) * invL;

  // attn rescale in place: attn currently holds raw scores
  float sv[4];
#pragma unroll
  for (int i = 0; i < 4; ++i) sv[i] = attn[(long)b * SEQ + i * 512 + tid];
#pragma unroll
  for (int i = 0; i < 4; ++i)
    attn[(long)b * SEQ + i * 512 + tid] = __expf(sv[i] - M) * invL;

  __syncthreads();
  // ctx[h] = sum_c pctx[c][h] * wc[c]
  float a = 0.f;
#pragma unroll 8
  for (int c = 0; c < CPB; ++c)
    a += bf2f(pctx[(long)(b * CPB + c) * HDIM + tid]) * wc[c];
  ctx[(long)b * HDIM + tid] = a;
}

extern "C" void kernel_launch(void* const* d_in, const int* in_sizes, int n_in,
                              void* d_out, int out_size, void* d_ws, size_t ws_size,
                              hipStream_t stream) {
  const float* enc = (const float*)d_in[0];
  const float* dec = (const float*)d_in[1];
  const float* W1  = (const float*)d_in[2];
  const float* b1  = (const float*)d_in[3];
  const float* W2  = (const float*)d_in[4];
  const float* b2  = (const float*)d_in[5];
  const float* V   = (const float*)d_in[6];
  const float* bv  = (const float*)d_in[7];

  float* out  = (float*)d_out;
  float* ctx  = out;                       // 64*512
  float* attn = out + NB * HDIM;           // 64*2048 (raw scores first, rescaled in place)

  char* ws = (char*)d_ws;
  unsigned short* w1k  = (unsigned short*)ws;                   // 512 KiB (k-step-major)
  float*          zful = (float*)(ws + 524288);                 // 128 KiB
  unsigned short* pctx = (unsigned short*)(ws + 655360);        // 2 MiB  (2048*512 bf16)
  float*          mlb  = (float*)(ws + 2752512);                // 16 KiB (2048*2 f32)
  (void)in_sizes; (void)n_in; (void)out_size; (void)ws_size;

  prep<<<256, 256, 0, stream>>>(W1, w1k, dec, W2, b1, b2, zful);
  gemm_fused<<<NBLK, 512, 0, stream>>>(enc, w1k, zful, V, bv, attn, pctx, mlb);
  combine<<<NB, 512, 0, stream>>>(attn, pctx, mlb, ctx);
}